// Round 1
// baseline (768.807 us; speedup 1.0000x reference)
//
#include <hip/hip_runtime.h>

// BlockXDiag forward: 64 GEMMs of [4096 x 768] x [768 x 256] (periodic block-tridiag).
// bf16 MFMA (16x16x32), fp32 accumulate. fp32->bf16 RTNE at LDS staging.

#define MB   64      // blocks per row/col
#define PB   256     // block size
#define NPR  16384   // MB*PB, row stride of x/out
#define BM   128
#define BN   128
#define BK   32
#define KTOT 768     // 3 * PB

typedef __bf16 bf16x8 __attribute__((ext_vector_type(8)));
typedef float  f32x4  __attribute__((ext_vector_type(4)));
typedef unsigned short u16x4 __attribute__((ext_vector_type(4)));

__device__ __forceinline__ unsigned short f2bf(float f) {
    unsigned u = __float_as_uint(f);
    u += 0x7fffu + ((u >> 16) & 1u);   // round-to-nearest-even
    return (unsigned short)(u >> 16);
}

__global__ __launch_bounds__(256, 2)
void bxd_kernel(const float* __restrict__ x,
                const float* __restrict__ Wd,
                const float* __restrict__ Wu,
                const float* __restrict__ Wl,
                const float* __restrict__ Wtr,
                const float* __restrict__ Wbl,
                float* __restrict__ out)
{
    __shared__ unsigned short sA[BM * BK];   // [row][k] bf16 bits
    __shared__ unsigned short sB[BN * BK];   // [n][k]  bf16 bits (B^T)

    const int i  = blockIdx.x >> 1;   // output block index 0..63
    const int nt = blockIdx.x & 1;    // n-tile within block (2 x 128)
    const int mt = blockIdx.y;        // m-tile (32 x 128)

    const int t    = threadIdx.x;
    const int lane = t & 63;
    const int wave = t >> 6;
    const int wm   = wave & 1;
    const int wn   = wave >> 1;
    const int quad = lane >> 4;
    const int l16  = lane & 15;

    // staging coords: 8 threads/row x 32 rows per pass, 4 passes
    const int srow = t >> 3;          // 0..31
    const int scol = (t & 7) * 4;     // 0,4,...,28

    // weight pointer + x-block index per K-chunk c (c=0: prev, 1: self, 2: next)
    const float* wptr[3];
    wptr[0] = (i == 0)      ? Wtr : (Wl + (size_t)(i - 1) * (PB * PB));
    wptr[1] = Wd + (size_t)i * (PB * PB);
    wptr[2] = (i == MB - 1) ? Wbl : (Wu + (size_t)i * (PB * PB));
    const int jblk[3] = { (i + MB - 1) & (MB - 1), i, (i + 1) & (MB - 1) };

    f32x4 acc[4][4];
    #pragma unroll
    for (int a = 0; a < 4; ++a)
        #pragma unroll
        for (int b = 0; b < 4; ++b)
            acc[a][b] = (f32x4){0.f, 0.f, 0.f, 0.f};

    for (int kt = 0; kt < KTOT / BK; ++kt) {
        const int c  = kt >> 3;       // which P-chunk (0..2)
        const int kb = kt & 7;        // BK-tile within chunk

        const float* aSrc = x + (size_t)(mt * BM + srow) * NPR
                              + jblk[c] * PB + kb * BK + scol;
        const float* bSrc = wptr[c] + (size_t)(nt * BN + srow) * PB
                              + kb * BK + scol;

        float4 av[4], bv[4];
        #pragma unroll
        for (int p = 0; p < 4; ++p) {
            av[p] = *(const float4*)(aSrc + (size_t)p * 32 * NPR);
            bv[p] = *(const float4*)(bSrc + (size_t)p * 32 * PB);
        }

        __syncthreads();   // previous iter's LDS reads done
        #pragma unroll
        for (int p = 0; p < 4; ++p) {
            u16x4 ra = { f2bf(av[p].x), f2bf(av[p].y), f2bf(av[p].z), f2bf(av[p].w) };
            *(u16x4*)&sA[(srow + p * 32) * BK + scol] = ra;
            u16x4 rb = { f2bf(bv[p].x), f2bf(bv[p].y), f2bf(bv[p].z), f2bf(bv[p].w) };
            *(u16x4*)&sB[(srow + p * 32) * BK + scol] = rb;
        }
        __syncthreads();   // tile visible

        bf16x8 afrag[4], bfrag[4];
        #pragma unroll
        for (int mi = 0; mi < 4; ++mi)
            afrag[mi] = *(const bf16x8*)&sA[(wm * 64 + mi * 16 + l16) * BK + quad * 8];
        #pragma unroll
        for (int ni = 0; ni < 4; ++ni)
            bfrag[ni] = *(const bf16x8*)&sB[(wn * 64 + ni * 16 + l16) * BK + quad * 8];

        #pragma unroll
        for (int mi = 0; mi < 4; ++mi)
            #pragma unroll
            for (int ni = 0; ni < 4; ++ni)
                acc[mi][ni] = __builtin_amdgcn_mfma_f32_16x16x32_bf16(
                    afrag[mi], bfrag[ni], acc[mi][ni], 0, 0, 0);
    }

    // epilogue: C/D layout col = lane&15 (n), row = quad*4 + reg (m)
    const int colb = i * PB + nt * BN + wn * 64;
    #pragma unroll
    for (int mi = 0; mi < 4; ++mi) {
        #pragma unroll
        for (int ni = 0; ni < 4; ++ni) {
            #pragma unroll
            for (int r = 0; r < 4; ++r) {
                const int row = mt * BM + wm * 64 + mi * 16 + quad * 4 + r;
                out[(size_t)row * NPR + colb + ni * 16 + l16] = acc[mi][ni][r];
            }
        }
    }
}

extern "C" void kernel_launch(void* const* d_in, const int* in_sizes, int n_in,
                              void* d_out, int out_size, void* d_ws, size_t ws_size,
                              hipStream_t stream) {
    const float* x   = (const float*)d_in[0];
    const float* Wd  = (const float*)d_in[1];
    const float* Wu  = (const float*)d_in[2];
    const float* Wl  = (const float*)d_in[3];
    const float* Wtr = (const float*)d_in[4];
    const float* Wbl = (const float*)d_in[5];
    float* out = (float*)d_out;

    dim3 grid(MB * 2, 4096 / BM, 1);   // (i, n-tile) fastest, m-tile in y
    dim3 block(256, 1, 1);
    hipLaunchKernelGGL(bxd_kernel, grid, block, 0, stream,
                       x, Wd, Wu, Wl, Wtr, Wbl, out);
}